// Round 2
// baseline (3069.204 us; speedup 1.0000x reference)
//
#include <hip/hip_runtime.h>
#include <stdint.h>

#define T_ 4
#define B_ 16
#define C_ 256
#define N_ 1024
#define HD_ 1024
#define HEADS_ 8
#define DH_ 32

__device__ __forceinline__ float toF(float x){ return x; }
__device__ __forceinline__ float toF(uint8_t x){ return (float)x; }

// GEMM (Y = W @ X) + optional bias + BN + LIF, t-loop inside block (LIF state in regs).
// X: [T,B,KDIM,N_] ; W: [ODIM,KDIM] ; bn: [4,ODIM] (gamma,beta,mean,var)
// OUT_MODE: 0 = write spike uint8 ; 1 = write float (resid float + spike)
template<int KDIM, int ODIM, bool HAS_BIAS, int OUT_MODE, typename TIn>
__global__ __launch_bounds__(256)
void gemm_bn_lif(const TIn* __restrict__ X, const float* __restrict__ W,
                 const float* __restrict__ bias, const float* __restrict__ bn,
                 const float* __restrict__ resid, void* __restrict__ out, float vth)
{
  const int tid = threadIdx.x;
  const int tx = tid & 15, ty = tid >> 4;
  const int b  = blockIdx.z;
  const int o0 = blockIdx.y * 64, n0 = blockIdx.x * 64;

  __shared__ float Xs[16][68];
  __shared__ float Ws[16][68];

  float gam[4], bet[4], mean[4], rstd[4], bia[4];
#pragma unroll
  for (int i=0;i<4;i++){
    int o = o0 + 4*ty + i;
    gam[i]  = bn[o];
    bet[i]  = bn[ODIM + o];
    mean[i] = bn[2*ODIM + o];
    rstd[i] = 1.0f / sqrtf(bn[3*ODIM + o] + 1e-5f);
    bia[i]  = HAS_BIAS ? bias[o] : 0.0f;
  }

  float v[16];
#pragma unroll
  for (int i=0;i<16;i++) v[i]=0.0f;

  for (int t=0;t<T_;t++){
    float acc[16];
#pragma unroll
    for (int i=0;i<16;i++) acc[i]=0.0f;
    const TIn* Xtb = X + (size_t)(t*B_+b)*KDIM*N_;
    for (int kc=0;kc<KDIM;kc+=16){
#pragma unroll
      for (int r=0;r<4;r++){
        int idx = tid + 256*r;
        int k = idx>>6, n = idx&63;
        Xs[k][n] = toF(Xtb[(size_t)(kc+k)*N_ + n0+n]);
      }
#pragma unroll
      for (int r=0;r<4;r++){
        int idx = tid + 256*r;
        int o = idx>>4, k = idx&15;
        Ws[k][o] = W[(size_t)(o0+o)*KDIM + kc+k];
      }
      __syncthreads();
#pragma unroll
      for (int k=0;k<16;k++){
        float4 xv = *(const float4*)&Xs[k][4*tx];
        float4 wv = *(const float4*)&Ws[k][4*ty];
        float xr[4]={xv.x,xv.y,xv.z,xv.w};
        float wr[4]={wv.x,wv.y,wv.z,wv.w};
#pragma unroll
        for (int i=0;i<4;i++)
#pragma unroll
          for (int j=0;j<4;j++) acc[i*4+j] += wr[i]*xr[j];
      }
      __syncthreads();
    }
    // epilogue: bias -> BN -> LIF -> output
#pragma unroll
    for (int i=0;i<4;i++){
#pragma unroll
      for (int j=0;j<4;j++){
        float y  = acc[i*4+j] + bia[i];
        float yb = (gam[i]*(y - mean[i]))*rstd[i] + bet[i];
        float vv = v[i*4+j];
        vv += (yb - vv)*0.5f;
        float s = (vv >= vth) ? 1.0f : 0.0f;
        v[i*4+j] = (s!=0.0f) ? 0.0f : vv;
        size_t oi = ((size_t)(t*B_+b)*ODIM + (o0+4*ty+i))*N_ + (n0+4*tx+j);
        if (OUT_MODE==0)      ((uint8_t*)out)[oi] = (uint8_t)s;
        else                  ((float*)out)[oi]   = resid[oi] + s;
      }
    }
  }
}

// kv[t,b,h,d,e] = sum_n k[d,n]*v[e,n] over binary byte spikes -> exact via popc(AND).
// (bytes are 0x00/0x01, so popc over ANDed 16-byte chunks counts matching 1s)
__global__ __launch_bounds__(256)
void kv_kernel(const uint8_t* __restrict__ ks, const uint8_t* __restrict__ vs,
               float* __restrict__ kvout)
{
  int blk = blockIdx.x;          // (t*B+b)*HEADS + h
  int h = blk & 7, tb = blk >> 3;
  int tid = threadIdx.x;
  int e = tid & 31, d0 = (tid >> 5) * 4;
  const uint8_t* kp = ks + ((size_t)tb*C_ + h*DH_)*N_;
  const uint8_t* vp = vs + ((size_t)tb*C_ + h*DH_)*N_;
  const uint4* vr = (const uint4*)(vp + (size_t)e*N_);
  const uint4* k0 = (const uint4*)(kp + (size_t)(d0+0)*N_);
  const uint4* k1 = (const uint4*)(kp + (size_t)(d0+1)*N_);
  const uint4* k2 = (const uint4*)(kp + (size_t)(d0+2)*N_);
  const uint4* k3 = (const uint4*)(kp + (size_t)(d0+3)*N_);
  int s0=0,s1=0,s2=0,s3=0;
  for (int q=0;q<N_/16;q++){
    uint4 vv = vr[q];
    uint4 a0 = k0[q], a1 = k1[q], a2 = k2[q], a3 = k3[q];
    s0 += __popc(a0.x&vv.x)+__popc(a0.y&vv.y)+__popc(a0.z&vv.z)+__popc(a0.w&vv.w);
    s1 += __popc(a1.x&vv.x)+__popc(a1.y&vv.y)+__popc(a1.z&vv.z)+__popc(a1.w&vv.w);
    s2 += __popc(a2.x&vv.x)+__popc(a2.y&vv.y)+__popc(a2.z&vv.z)+__popc(a2.w&vv.w);
    s3 += __popc(a3.x&vv.x)+__popc(a3.y&vv.y)+__popc(a3.z&vv.z)+__popc(a3.w&vv.w);
  }
  float* kvp = kvout + (size_t)blk*DH_*DH_;
  kvp[(d0+0)*DH_ + e] = (float)s0;
  kvp[(d0+1)*DH_ + e] = (float)s1;
  kvp[(d0+2)*DH_ + e] = (float)s2;
  kvp[(d0+3)*DH_ + e] = (float)s3;
}

// a[e,n] = 0.125 * sum_d q[d,n]*kv[d,e] ; LIF vth=0.5 ; exact dyadic arithmetic.
__global__ __launch_bounds__(256)
void attn_lif_kernel(const uint8_t* __restrict__ qs, const float* __restrict__ kv,
                     uint8_t* __restrict__ as_)
{
  int tid = threadIdx.x;
  int n = blockIdx.x*256 + tid;
  int h = blockIdx.y, b = blockIdx.z;
  __shared__ float kvL[DH_*DH_];
  float v[DH_];
#pragma unroll
  for (int e=0;e<DH_;e++) v[e]=0.0f;
  for (int t=0;t<T_;t++){
    const float* kvp = kv + ((size_t)((t*B_+b)*HEADS_+h))*DH_*DH_;
    __syncthreads();
#pragma unroll
    for (int r=0;r<4;r++) kvL[tid+256*r] = kvp[tid+256*r];
    __syncthreads();
    const uint8_t* qp = qs + ((size_t)(t*B_+b)*C_ + h*DH_)*N_ + n;
    float qv[DH_];
#pragma unroll
    for (int d=0;d<DH_;d++) qv[d] = (float)qp[(size_t)d*N_];
    uint8_t* op = as_ + ((size_t)(t*B_+b)*C_ + h*DH_)*N_ + n;
#pragma unroll
    for (int e=0;e<DH_;e++){
      float a=0.0f;
#pragma unroll
      for (int d=0;d<DH_;d++) a += qv[d]*kvL[d*DH_+e];
      a *= 0.125f;
      float vv = v[e];
      vv += (a - vv)*0.5f;
      float s = (vv >= 0.5f) ? 1.0f : 0.0f;
      v[e] = (s!=0.0f) ? 0.0f : vv;
      op[(size_t)e*N_] = (uint8_t)s;
    }
  }
}

extern "C" void kernel_launch(void* const* d_in, const int* in_sizes, int n_in,
                              void* d_out, int out_size, void* d_ws, size_t ws_size,
                              hipStream_t stream)
{
  const float* x      = (const float*)d_in[0];
  const float* wq     = (const float*)d_in[2];
  const float* bn_q   = (const float*)d_in[3];
  const float* wk     = (const float*)d_in[4];
  const float* bn_k   = (const float*)d_in[5];
  const float* wv     = (const float*)d_in[6];
  const float* bn_v   = (const float*)d_in[7];
  const float* wproj  = (const float*)d_in[8];
  const float* bproj  = (const float*)d_in[9];
  const float* bnproj = (const float*)d_in[10];
  const float* wfc1   = (const float*)d_in[11];
  const float* bfc1   = (const float*)d_in[12];
  const float* bnfc1  = (const float*)d_in[13];
  const float* wfc2   = (const float*)d_in[14];
  const float* bfc2   = (const float*)d_in[15];
  const float* bnfc2  = (const float*)d_in[16];

  char* ws = (char*)d_ws;
  const size_t S1 = (size_t)T_*B_*C_*N_;   // 16,777,216 elements
  uint8_t* qs  = (uint8_t*)ws;             // S1 bytes
  uint8_t* ksb = qs  + S1;
  uint8_t* vsb = ksb + S1;
  uint8_t* asb = vsb + S1;
  uint8_t* h1s = asb + S1;                 // 4*S1 bytes (T,B,HD,N)
  float*   kvb = (float*)(ws + 8*S1);      // 2 MB
  float*   xnew= (float*)(ws + 8*S1 + (size_t)T_*B_*HEADS_*DH_*DH_*sizeof(float)); // 67 MB

  dim3 blk(256);
  dim3 g256(16,4,16);     // (n_tiles, o_tiles, b)
  dim3 g1024(16,16,16);

  gemm_bn_lif<C_,C_,false,0,float><<<g256,blk,0,stream>>>(x, wq, nullptr, bn_q, nullptr, qs, 1.0f);
  gemm_bn_lif<C_,C_,false,0,float><<<g256,blk,0,stream>>>(x, wk, nullptr, bn_k, nullptr, ksb, 1.0f);
  gemm_bn_lif<C_,C_,false,0,float><<<g256,blk,0,stream>>>(x, wv, nullptr, bn_v, nullptr, vsb, 1.0f);
  kv_kernel<<<dim3(T_*B_*HEADS_),blk,0,stream>>>(ksb, vsb, kvb);
  attn_lif_kernel<<<dim3(4,HEADS_,B_),blk,0,stream>>>(qs, kvb, asb);
  gemm_bn_lif<C_,C_,true,1,uint8_t><<<g256,blk,0,stream>>>(asb, wproj, bproj, bnproj, x, xnew, 1.0f);
  gemm_bn_lif<C_,HD_,true,0,float><<<g1024,blk,0,stream>>>(xnew, wfc1, bfc1, bnfc1, nullptr, h1s, 1.0f);
  gemm_bn_lif<HD_,C_,true,1,uint8_t><<<g256,blk,0,stream>>>(h1s, wfc2, bfc2, bnfc2, xnew, (float*)d_out, 1.0f);
}

// Round 4
// 1943.731 us; speedup vs baseline: 1.5790x; 1.5790x over previous
//
#include <hip/hip_runtime.h>
#include <stdint.h>

#define T_ 4
#define B_ 16
#define C_ 256
#define N_ 1024
#define HD_ 1024
#define HEADS_ 8
#define DH_ 32

typedef float v2f __attribute__((ext_vector_type(2)));

// Wt[k][ooff+o] = W[o][k].  W: [O][K] row-major.  grid (K/32, O/32), 256 thr.
__global__ __launch_bounds__(256)
void transW(const float* __restrict__ W, float* __restrict__ Wt,
            int O, int K, int ostride, int ooff)
{
  __shared__ float tl[32][33];
  int k0 = blockIdx.x*32, o0 = blockIdx.y*32;
  int tid = threadIdx.x;
  int a = tid & 31, bq = tid >> 5;                 // a: fast dim, bq: 0..7
#pragma unroll
  for (int i=0;i<4;i++)
    tl[bq+8*i][a] = W[(size_t)(o0+bq+8*i)*K + k0 + a];
  __syncthreads();
#pragma unroll
  for (int i=0;i<4;i++)
    Wt[(size_t)(k0+bq+8*i)*ostride + ooff + o0 + a] = tl[a][bq+8*i];
}

__global__ __launch_bounds__(256)
void packBn3(const float* __restrict__ a, const float* __restrict__ b,
             const float* __restrict__ c, float* __restrict__ o)
{
  int i = blockIdx.x*256 + threadIdx.x;            // 0..1023 = [4][256]
  int r = i >> 8, ci = i & 255;
  o[(size_t)r*768 + ci]       = a[i];
  o[(size_t)r*768 + 256 + ci] = b[i];
  o[(size_t)r*768 + 512 + ci] = c[i];
}

__device__ __forceinline__ float4 loadX4(const float* p){ return *(const float4*)p; }
__device__ __forceinline__ float4 loadX4(const uint8_t* p){
  uchar4 u = *(const uchar4*)p;
  return make_float4((float)u.x,(float)u.y,(float)u.z,(float)u.w);
}

// Y = Wt^T @ X (+bias) -> BN -> LIF, t-loop inside block (LIF state in regs).
// X: [T,B,KDIM,N] (float or u8 spikes); Wt: [KDIM][ODIM] (pre-transposed);
// bn: [4][ODIM] gamma,beta,mean,var.
// MODE 0: u8 spikes out [T,B,ODIM,N]; MODE 1: float out = resid + spike.
// Numeric contract: per output, strictly k-ascending fp32 FMA chain (bit-path
// matches the np reference's sequential einsum; verified absmax 0.0 in R2).
// v_pk_fma_f32 = two independent IEEE fp32 FMAs (two n-columns per chain).
template<int KDIM,int ODIM,bool HAS_BIAS,int MODE,typename TIn>
__global__ __launch_bounds__(256)
void vec_gemm(const TIn* __restrict__ X, const float* __restrict__ Wt,
              const float* __restrict__ bias, const float* __restrict__ bn,
              const float* __restrict__ resid, void* __restrict__ out, float vth)
{
  __shared__ __align__(16) float Xs[16*128];
  __shared__ __align__(16) float Ws2[16*130];      // [k][2*o] duplicated pairs

  const int tid = threadIdx.x;
  const int tx = tid & 15, ty = tid >> 4;
  const int b = blockIdx.z, o0 = blockIdx.y*64, n0 = blockIdx.x*128;

  float gam[4], bet[4], mean[4], rstd[4], bia[4];
#pragma unroll
  for (int i=0;i<4;i++){
    int o = o0 + 4*ty + i;
    gam[i]  = bn[o];
    bet[i]  = bn[ODIM + o];
    mean[i] = bn[2*ODIM + o];
    rstd[i] = 1.0f / sqrtf(bn[3*ODIM + o] + 1e-5f);
    bia[i]  = HAS_BIAS ? bias[o] : 0.0f;
  }

  v2f vli[4][4];
#pragma unroll
  for (int i=0;i<4;i++)
#pragma unroll
    for (int j=0;j<4;j++) vli[i][j] = (v2f){0.f,0.f};

  const int skk = tid >> 4;              // W stage: k row 0..15
  const int so4 = (tid & 15) * 4;        // W stage: o quad
  const int sxk = tid >> 5;              // X stage: k row 0..7 (x2)
  const int sxn = (tid & 31) * 4;        // X stage: n quad

  for (int t=0;t<T_;t++){
    v2f acc[4][4];
#pragma unroll
    for (int i=0;i<4;i++)
#pragma unroll
      for (int j=0;j<4;j++) acc[i][j] = (v2f){0.f,0.f};

    const TIn* Xtb = X + (size_t)(t*B_+b)*KDIM*N_;
    for (int kc=0;kc<KDIM;kc+=16){
      __syncthreads();
      float4 wv = *(const float4*)&Wt[(size_t)(kc+skk)*ODIM + o0 + so4];
#pragma unroll
      for (int j=0;j<4;j++){
        float w = (j==0)?wv.x:(j==1)?wv.y:(j==2)?wv.z:wv.w;
        *(v2f*)&Ws2[skk*130 + 2*(so4+j)] = (v2f){w,w};
      }
#pragma unroll
      for (int kk=0;kk<2;kk++){
        int k = sxk + 8*kk;
        *(float4*)&Xs[k*128 + sxn] = loadX4(Xtb + (size_t)(kc+k)*N_ + n0 + sxn);
      }
      __syncthreads();
#pragma unroll
      for (int k=0;k<16;k++){
        v2f w2[4];
#pragma unroll
        for (int i=0;i<4;i++) w2[i] = *(const v2f*)&Ws2[k*130 + 8*ty + 2*i];
        float4 xa = *(const float4*)&Xs[k*128 + tx*8];
        float4 xb = *(const float4*)&Xs[k*128 + tx*8 + 4];
        v2f x2[4];
        x2[0] = (v2f){xa.x, xa.y}; x2[1] = (v2f){xa.z, xa.w};
        x2[2] = (v2f){xb.x, xb.y}; x2[3] = (v2f){xb.z, xb.w};
#pragma unroll
        for (int i=0;i<4;i++)
#pragma unroll
          for (int j=0;j<4;j++)
            asm("v_pk_fma_f32 %0, %1, %2, %0"
                : "+v"(acc[i][j]) : "v"(w2[i]), "v"(x2[j]));
      }
    }
    // epilogue: bias -> BN -> LIF -> store (identical formula chain to R2)
#pragma unroll
    for (int i=0;i<4;i++){
      int o = o0 + 4*ty + i;
      float sv[8];
#pragma unroll
      for (int j=0;j<8;j++){
        float y  = acc[i][j>>1][j&1] + bia[i];
        float yb = (gam[i]*(y - mean[i]))*rstd[i] + bet[i];
        float vv = vli[i][j>>1][j&1];
        vv += (yb - vv)*0.5f;
        float s = (vv >= vth) ? 1.0f : 0.0f;
        vli[i][j>>1][j&1] = (s!=0.0f) ? 0.0f : vv;
        sv[j] = s;
      }
      size_t oi = ((size_t)(t*B_+b)*ODIM + o)*N_ + n0 + tx*8;
      if (MODE==0){
        union { uint2 u; uint8_t bt[8]; } pk;
#pragma unroll
        for (int j=0;j<8;j++) pk.bt[j] = (uint8_t)sv[j];
        *(uint2*)((uint8_t*)out + oi) = pk.u;
      } else {
        float4 r0 = *(const float4*)&resid[oi];
        float4 r1 = *(const float4*)&resid[oi+4];
        float4 w0 = make_float4(r0.x+sv[0], r0.y+sv[1], r0.z+sv[2], r0.w+sv[3]);
        float4 w1 = make_float4(r1.x+sv[4], r1.y+sv[5], r1.z+sv[6], r1.w+sv[7]);
        *(float4*)&((float*)out)[oi]   = w0;
        *(float4*)&((float*)out)[oi+4] = w1;
      }
    }
  }
}

// kv[t,b,h,d,e] = sum_n k[d,n]*v[e,n] over binary byte spikes (exact popc).
// qkv packed: [T*B, 768, N] with rows 0..255=q, 256..511=k, 512..767=v.
__global__ __launch_bounds__(256)
void kv_kernel(const uint8_t* __restrict__ qkv, float* __restrict__ kvout)
{
  int blk = blockIdx.x;          // (t*B+b)*HEADS + h
  int h = blk & 7, tb = blk >> 3;
  int tid = threadIdx.x;
  int e = tid & 31, d0 = (tid >> 5) * 4;
  const uint8_t* kp = qkv + ((size_t)tb*768 + 256 + h*DH_)*N_;
  const uint8_t* vp = qkv + ((size_t)tb*768 + 512 + h*DH_)*N_;
  const uint4* vr = (const uint4*)(vp + (size_t)e*N_);
  const uint4* k0 = (const uint4*)(kp + (size_t)(d0+0)*N_);
  const uint4* k1 = (const uint4*)(kp + (size_t)(d0+1)*N_);
  const uint4* k2 = (const uint4*)(kp + (size_t)(d0+2)*N_);
  const uint4* k3 = (const uint4*)(kp + (size_t)(d0+3)*N_);
  int s0=0,s1=0,s2=0,s3=0;
  for (int q=0;q<N_/16;q++){
    uint4 vv = vr[q];
    uint4 a0 = k0[q], a1 = k1[q], a2 = k2[q], a3 = k3[q];
    s0 += __popc(a0.x&vv.x)+__popc(a0.y&vv.y)+__popc(a0.z&vv.z)+__popc(a0.w&vv.w);
    s1 += __popc(a1.x&vv.x)+__popc(a1.y&vv.y)+__popc(a1.z&vv.z)+__popc(a1.w&vv.w);
    s2 += __popc(a2.x&vv.x)+__popc(a2.y&vv.y)+__popc(a2.z&vv.z)+__popc(a2.w&vv.w);
    s3 += __popc(a3.x&vv.x)+__popc(a3.y&vv.y)+__popc(a3.z&vv.z)+__popc(a3.w&vv.w);
  }
  float* kvp = kvout + (size_t)blk*DH_*DH_;
  kvp[(d0+0)*DH_ + e] = (float)s0;
  kvp[(d0+1)*DH_ + e] = (float)s1;
  kvp[(d0+2)*DH_ + e] = (float)s2;
  kvp[(d0+3)*DH_ + e] = (float)s3;
}

// a[e,n] = 0.125 * sum_d q[d,n]*kv[d,e]; LIF vth=0.5 (exact dyadic).
// writes as_ [T,B,C,N] u8 spikes.
__global__ __launch_bounds__(256)
void attn_lif_kernel(const uint8_t* __restrict__ qkv, const float* __restrict__ kv,
                     uint8_t* __restrict__ as_)
{
  int tid = threadIdx.x;
  int n = blockIdx.x*256 + tid;
  int h = blockIdx.y, b = blockIdx.z;
  __shared__ float kvL[DH_*DH_];
  float v[DH_];
#pragma unroll
  for (int e=0;e<DH_;e++) v[e]=0.0f;
  for (int t=0;t<T_;t++){
    const float* kvp = kv + ((size_t)((t*B_+b)*HEADS_+h))*DH_*DH_;
    __syncthreads();
#pragma unroll
    for (int r=0;r<4;r++) kvL[tid+256*r] = kvp[tid+256*r];
    __syncthreads();
    const uint8_t* qp = qkv + ((size_t)(t*B_+b)*768 + h*DH_)*N_ + n;
    float qv[DH_];
#pragma unroll
    for (int d=0;d<DH_;d++) qv[d] = (float)qp[(size_t)d*N_];
    uint8_t* op = as_ + ((size_t)(t*B_+b)*C_ + h*DH_)*N_ + n;
#pragma unroll
    for (int e=0;e<DH_;e++){
      float a=0.0f;
#pragma unroll
      for (int d=0;d<DH_;d++) a += qv[d]*kvL[d*DH_+e];
      a *= 0.125f;
      float vv = v[e];
      vv += (a - vv)*0.5f;
      float s = (vv >= 0.5f) ? 1.0f : 0.0f;
      v[e] = (s!=0.0f) ? 0.0f : vv;
      op[(size_t)e*N_] = (uint8_t)s;
    }
  }
}

extern "C" void kernel_launch(void* const* d_in, const int* in_sizes, int n_in,
                              void* d_out, int out_size, void* d_ws, size_t ws_size,
                              hipStream_t stream)
{
  const float* x      = (const float*)d_in[0];
  const float* wq     = (const float*)d_in[2];
  const float* bn_q   = (const float*)d_in[3];
  const float* wk     = (const float*)d_in[4];
  const float* bn_k   = (const float*)d_in[5];
  const float* wv     = (const float*)d_in[6];
  const float* bn_v   = (const float*)d_in[7];
  const float* wproj  = (const float*)d_in[8];
  const float* bproj  = (const float*)d_in[9];
  const float* bnproj = (const float*)d_in[10];
  const float* wfc1   = (const float*)d_in[11];
  const float* bfc1   = (const float*)d_in[12];
  const float* bnfc1  = (const float*)d_in[13];
  const float* wfc2   = (const float*)d_in[14];
  const float* bfc2   = (const float*)d_in[15];
  const float* bnfc2  = (const float*)d_in[16];

  char* ws = (char*)d_ws;
  const size_t TB = (size_t)T_*B_;
  // region A (67.1 MB): qkv spikes + attn spikes, later overlaid by h1s
  uint8_t* qkv = (uint8_t*)ws;                       // TB*768*N = 50.3 MB
  uint8_t* as_ = (uint8_t*)ws + TB*768*N_;           // TB*256*N = 16.8 MB
  uint8_t* h1s = (uint8_t*)ws;                       // TB*1024*N = 67.1 MB (overlay)
  size_t off = TB*768*N_ + TB*(size_t)C_*N_;         // = TB*1024*N
  float* xnew = (float*)(ws + off); off += TB*(size_t)C_*N_*4;   // 67.1 MB
  float* WtQ  = (float*)(ws + off); off += (size_t)C_*768*4;
  float* WtP  = (float*)(ws + off); off += (size_t)C_*C_*4;
  float* WtF1 = (float*)(ws + off); off += (size_t)C_*HD_*4;
  float* WtF2 = (float*)(ws + off); off += (size_t)HD_*C_*4;
  float* bnQ  = (float*)(ws + off); off += 4*768*4;
  float* kvb  = (float*)(ws + off); off += TB*HEADS_*DH_*DH_*4;

  dim3 blk(256);
  // weight pre-transposes (coalesced GEMM staging); QKV fused into ODIM=768
  transW<<<dim3(8,8),blk,0,stream>>>(wq, WtQ, 256, 256, 768, 0);
  transW<<<dim3(8,8),blk,0,stream>>>(wk, WtQ, 256, 256, 768, 256);
  transW<<<dim3(8,8),blk,0,stream>>>(wv, WtQ, 256, 256, 768, 512);
  transW<<<dim3(8,8),blk,0,stream>>>(wproj, WtP, 256, 256, 256, 0);
  transW<<<dim3(8,32),blk,0,stream>>>(wfc1, WtF1, 1024, 256, 1024, 0);
  transW<<<dim3(32,8),blk,0,stream>>>(wfc2, WtF2, 256, 1024, 256, 0);
  packBn3<<<dim3(4),blk,0,stream>>>(bn_q, bn_k, bn_v, bnQ);

  // fused QKV GEMM -> spikes
  vec_gemm<C_,768,false,0,float><<<dim3(8,12,16),blk,0,stream>>>(
      x, WtQ, nullptr, bnQ, nullptr, qkv, 1.0f);
  kv_kernel<<<dim3(T_*B_*HEADS_),blk,0,stream>>>(qkv, kvb);
  attn_lif_kernel<<<dim3(4,HEADS_,B_),blk,0,stream>>>(qkv, kvb, as_);
  // proj -> xnew = x + attn spike
  vec_gemm<C_,C_,true,1,uint8_t><<<dim3(8,4,16),blk,0,stream>>>(
      as_, WtP, bproj, bnproj, x, xnew, 1.0f);
  // fc1 -> h1 spikes (overlays dead qkv/as_)
  vec_gemm<C_,HD_,true,0,float><<<dim3(8,16,16),blk,0,stream>>>(
      xnew, WtF1, bfc1, bnfc1, nullptr, h1s, 1.0f);
  // fc2 -> out = xnew + mlp spike
  vec_gemm<HD_,C_,true,1,uint8_t><<<dim3(8,4,16),blk,0,stream>>>(
      h1s, WtF2, bfc2, bnfc2, xnew, d_out, 1.0f);
}

// Round 5
// 1530.400 us; speedup vs baseline: 2.0055x; 1.2701x over previous
//
#include <hip/hip_runtime.h>
#include <stdint.h>

#define T_ 4
#define B_ 16
#define C_ 256
#define N_ 1024
#define HD_ 1024
#define HEADS_ 8
#define DH_ 32

typedef float v2f __attribute__((ext_vector_type(2)));

// v_pk_fma_f32 with op_sel broadcast of one 32-bit half of src0 to both halves.
// Two independent IEEE fp32 FMAs per op; bit-exact per-output chains.
#define PKL(a, w, x) asm("v_pk_fma_f32 %0, %1, %2, %0 op_sel:[0,0,0] op_sel_hi:[0,1,1]" : "+v"(a) : "v"(w), "v"(x))
#define PKH(a, w, x) asm("v_pk_fma_f32 %0, %1, %2, %0 op_sel:[1,0,0] op_sel_hi:[1,1,1]" : "+v"(a) : "v"(w), "v"(x))

// Wt[k][ooff+o] = W[o][k].  W: [O][K] row-major.  grid (K/32, O/32), 256 thr.
__global__ __launch_bounds__(256)
void transW(const float* __restrict__ W, float* __restrict__ Wt,
            int O, int K, int ostride, int ooff)
{
  __shared__ float tl[32][33];
  int k0 = blockIdx.x*32, o0 = blockIdx.y*32;
  int tid = threadIdx.x;
  int a = tid & 31, bq = tid >> 5;
#pragma unroll
  for (int i=0;i<4;i++)
    tl[bq+8*i][a] = W[(size_t)(o0+bq+8*i)*K + k0 + a];
  __syncthreads();
#pragma unroll
  for (int i=0;i<4;i++)
    Wt[(size_t)(k0+bq+8*i)*ostride + ooff + o0 + a] = tl[a][bq+8*i];
}

__global__ __launch_bounds__(256)
void packBn3(const float* __restrict__ a, const float* __restrict__ b,
             const float* __restrict__ c, float* __restrict__ o)
{
  int i = blockIdx.x*256 + threadIdx.x;            // 0..1023 = [4][256]
  int r = i >> 8, ci = i & 255;
  o[(size_t)r*768 + ci]       = a[i];
  o[(size_t)r*768 + 256 + ci] = b[i];
  o[(size_t)r*768 + 512 + ci] = c[i];
}

template<typename T> struct VecT;
template<> struct VecT<float>  { using t = float4; };
template<> struct VecT<uint8_t>{ using t = uchar4; };
__device__ __forceinline__ float4 cvt4(float4 v){ return v; }
__device__ __forceinline__ float4 cvt4(uchar4 u){
  return make_float4((float)u.x,(float)u.y,(float)u.z,(float)u.w);
}

// Y = Wt^T @ X (+bias) -> BN -> LIF, t-loop inside block (LIF state in regs).
// X: [T,B,KDIM,N] (float or u8 spikes); Wt: [KDIM][ODIM] pre-transposed;
// bn: [4][ODIM] gamma,beta,mean,var.
// Block tile 128o x 128n; thread: 8o (8*ty..+7) x 8n (tx*4, 64+tx*4).
// MODE 0: u8 spikes out [T,B,ODIM,N]; MODE 1: float out = resid + spike.
// Numeric contract: per output, strictly k-ascending fp32 FMA chain
// (bit-path matched np ref: absmax 0.0 in R2/R4).
template<int KDIM,int ODIM,bool HAS_BIAS,int MODE,typename TIn>
__global__ __launch_bounds__(256,2)
void vec_gemm(const TIn* __restrict__ X, const float* __restrict__ Wt,
              const float* __restrict__ bias, const float* __restrict__ bn,
              const float* __restrict__ resid, void* __restrict__ out, float vth)
{
  using XV = typename VecT<TIn>::t;
  constexpr int NC = KDIM/16;
  __shared__ __align__(16) float Xs[16*128];
  __shared__ __align__(16) float Ws[16*128];

  const int tid = threadIdx.x;
  const int tx = tid & 15, ty = tid >> 4;
  const int b = blockIdx.z, o0 = blockIdx.y*128, n0 = blockIdx.x*128;
  const int sk = tid >> 4, sc = (tid & 15)*8;

  v2f vli[8][4];
#pragma unroll
  for (int i=0;i<8;i++)
#pragma unroll
    for (int j=0;j<4;j++) vli[i][j] = (v2f){0.f,0.f};

  // prefetch chunk (t=0,c=0)
  float4 wr0 = *(const float4*)&Wt[(size_t)sk*ODIM + o0+sc];
  float4 wr1 = *(const float4*)&Wt[(size_t)sk*ODIM + o0+sc+4];
  XV xr0 = *(const XV*)(X + (size_t)b*KDIM*N_ + (size_t)sk*N_ + n0+sc);
  XV xr1 = *(const XV*)(X + (size_t)b*KDIM*N_ + (size_t)sk*N_ + n0+sc+4);

  for (int t=0;t<T_;t++){
    v2f acc[8][4];
#pragma unroll
    for (int i=0;i<8;i++)
#pragma unroll
      for (int j=0;j<4;j++) acc[i][j] = (v2f){0.f,0.f};

    for (int c=0;c<NC;c++){
      __syncthreads();
      *(float4*)&Ws[sk*128+sc]   = wr0;
      *(float4*)&Ws[sk*128+sc+4] = wr1;
      *(float4*)&Xs[sk*128+sc]   = cvt4(xr0);
      *(float4*)&Xs[sk*128+sc+4] = cvt4(xr1);
      __syncthreads();
      // prefetch next chunk (overlaps with compute below)
      {
        int nt = t, nc = c+1;
        if (nc==NC){ nc=0; nt=t+1; }
        if (nt<T_){
          const TIn* Xn = X + (size_t)(nt*B_+b)*KDIM*N_;
          wr0 = *(const float4*)&Wt[(size_t)(nc*16+sk)*ODIM + o0+sc];
          wr1 = *(const float4*)&Wt[(size_t)(nc*16+sk)*ODIM + o0+sc+4];
          xr0 = *(const XV*)(Xn + (size_t)(nc*16+sk)*N_ + n0+sc);
          xr1 = *(const XV*)(Xn + (size_t)(nc*16+sk)*N_ + n0+sc+4);
        }
      }
#pragma unroll
      for (int k=0;k<16;k++){
        v2f wa = *(const v2f*)&Ws[k*128 + 8*ty];
        v2f wb = *(const v2f*)&Ws[k*128 + 8*ty + 2];
        v2f wc = *(const v2f*)&Ws[k*128 + 8*ty + 4];
        v2f wd = *(const v2f*)&Ws[k*128 + 8*ty + 6];
        v2f xf[4];
        xf[0] = *(const v2f*)&Xs[k*128 + tx*4];
        xf[1] = *(const v2f*)&Xs[k*128 + tx*4 + 2];
        xf[2] = *(const v2f*)&Xs[k*128 + 64 + tx*4];
        xf[3] = *(const v2f*)&Xs[k*128 + 64 + tx*4 + 2];
#pragma unroll
        for (int j=0;j<4;j++){
          PKL(acc[0][j], wa, xf[j]);
          PKH(acc[1][j], wa, xf[j]);
          PKL(acc[2][j], wb, xf[j]);
          PKH(acc[3][j], wb, xf[j]);
          PKL(acc[4][j], wc, xf[j]);
          PKH(acc[5][j], wc, xf[j]);
          PKL(acc[6][j], wd, xf[j]);
          PKH(acc[7][j], wd, xf[j]);
        }
      }
    }
    // epilogue: bias -> BN -> LIF -> store (identical formula chain to R2/R4)
#pragma unroll
    for (int i=0;i<8;i++){
      int o = o0 + 8*ty + i;
      float g  = bn[o];
      float be = bn[ODIM + o];
      float m  = bn[2*ODIM + o];
      float rs = 1.0f / sqrtf(bn[3*ODIM + o] + 1e-5f);
      float bi = HAS_BIAS ? bias[o] : 0.0f;
      float sv[8];
#pragma unroll
      for (int jj=0;jj<8;jj++){
        float y  = acc[i][jj>>1][jj&1] + bi;
        float yb = (g*(y - m))*rs + be;
        float vv = vli[i][jj>>1][jj&1];
        vv += (yb - vv)*0.5f;
        float s = (vv >= vth) ? 1.0f : 0.0f;
        vli[i][jj>>1][jj&1] = (s!=0.0f) ? 0.0f : vv;
        sv[jj] = s;
      }
      size_t base = ((size_t)(t*B_+b)*ODIM + o)*N_ + n0;
      if (MODE==0){
        uchar4 pa, pb;
        pa.x=(uint8_t)sv[0]; pa.y=(uint8_t)sv[1]; pa.z=(uint8_t)sv[2]; pa.w=(uint8_t)sv[3];
        pb.x=(uint8_t)sv[4]; pb.y=(uint8_t)sv[5]; pb.z=(uint8_t)sv[6]; pb.w=(uint8_t)sv[7];
        *(uchar4*)((uint8_t*)out + base + tx*4)      = pa;
        *(uchar4*)((uint8_t*)out + base + 64 + tx*4) = pb;
      } else {
        float4 r0 = *(const float4*)&resid[base + tx*4];
        float4 r1 = *(const float4*)&resid[base + 64 + tx*4];
        float4 w0 = make_float4(r0.x+sv[0], r0.y+sv[1], r0.z+sv[2], r0.w+sv[3]);
        float4 w1 = make_float4(r1.x+sv[4], r1.y+sv[5], r1.z+sv[6], r1.w+sv[7]);
        *(float4*)&((float*)out)[base + tx*4]      = w0;
        *(float4*)&((float*)out)[base + 64 + tx*4] = w1;
      }
    }
  }
}

// kv[t,b,h,d,e] = sum_n k[d,n]*v[e,n] over binary byte spikes (exact popc).
// qkv packed: [T*B, 768, N] rows 0..255=q, 256..511=k, 512..767=v.
__global__ __launch_bounds__(256)
void kv_kernel(const uint8_t* __restrict__ qkv, float* __restrict__ kvout)
{
  int blk = blockIdx.x;          // (t*B+b)*HEADS + h
  int h = blk & 7, tb = blk >> 3;
  int tid = threadIdx.x;
  int e = tid & 31, d0 = (tid >> 5) * 4;
  const uint8_t* kp = qkv + ((size_t)tb*768 + 256 + h*DH_)*N_;
  const uint8_t* vp = qkv + ((size_t)tb*768 + 512 + h*DH_)*N_;
  const uint4* vr = (const uint4*)(vp + (size_t)e*N_);
  const uint4* k0 = (const uint4*)(kp + (size_t)(d0+0)*N_);
  const uint4* k1 = (const uint4*)(kp + (size_t)(d0+1)*N_);
  const uint4* k2 = (const uint4*)(kp + (size_t)(d0+2)*N_);
  const uint4* k3 = (const uint4*)(kp + (size_t)(d0+3)*N_);
  int s0=0,s1=0,s2=0,s3=0;
  for (int q=0;q<N_/16;q++){
    uint4 vv = vr[q];
    uint4 a0 = k0[q], a1 = k1[q], a2 = k2[q], a3 = k3[q];
    s0 += __popc(a0.x&vv.x)+__popc(a0.y&vv.y)+__popc(a0.z&vv.z)+__popc(a0.w&vv.w);
    s1 += __popc(a1.x&vv.x)+__popc(a1.y&vv.y)+__popc(a1.z&vv.z)+__popc(a1.w&vv.w);
    s2 += __popc(a2.x&vv.x)+__popc(a2.y&vv.y)+__popc(a2.z&vv.z)+__popc(a2.w&vv.w);
    s3 += __popc(a3.x&vv.x)+__popc(a3.y&vv.y)+__popc(a3.z&vv.z)+__popc(a3.w&vv.w);
  }
  float* kvp = kvout + (size_t)blk*DH_*DH_;
  kvp[(d0+0)*DH_ + e] = (float)s0;
  kvp[(d0+1)*DH_ + e] = (float)s1;
  kvp[(d0+2)*DH_ + e] = (float)s2;
  kvp[(d0+3)*DH_ + e] = (float)s3;
}

// a[e,n] = 0.125 * sum_d q[d,n]*kv[d,e]; LIF vth=0.5 (exact dyadic).
// writes as_ [T,B,C,N] u8 spikes.
__global__ __launch_bounds__(256)
void attn_lif_kernel(const uint8_t* __restrict__ qkv, const float* __restrict__ kv,
                     uint8_t* __restrict__ as_)
{
  int tid = threadIdx.x;
  int n = blockIdx.x*256 + tid;
  int h = blockIdx.y, b = blockIdx.z;
  __shared__ float kvL[DH_*DH_];
  float v[DH_];
#pragma unroll
  for (int e=0;e<DH_;e++) v[e]=0.0f;
  for (int t=0;t<T_;t++){
    const float* kvp = kv + ((size_t)((t*B_+b)*HEADS_+h))*DH_*DH_;
    __syncthreads();
#pragma unroll
    for (int r=0;r<4;r++) kvL[tid+256*r] = kvp[tid+256*r];
    __syncthreads();
    const uint8_t* qp = qkv + ((size_t)(t*B_+b)*768 + h*DH_)*N_ + n;
    float qv[DH_];
#pragma unroll
    for (int d=0;d<DH_;d++) qv[d] = (float)qp[(size_t)d*N_];
    uint8_t* op = as_ + ((size_t)(t*B_+b)*C_ + h*DH_)*N_ + n;
#pragma unroll
    for (int e=0;e<DH_;e++){
      float a=0.0f;
#pragma unroll
      for (int d=0;d<DH_;d++) a += qv[d]*kvL[d*DH_+e];
      a *= 0.125f;
      float vv = v[e];
      vv += (a - vv)*0.5f;
      float s = (vv >= 0.5f) ? 1.0f : 0.0f;
      v[e] = (s!=0.0f) ? 0.0f : vv;
      op[(size_t)e*N_] = (uint8_t)s;
    }
  }
}

extern "C" void kernel_launch(void* const* d_in, const int* in_sizes, int n_in,
                              void* d_out, int out_size, void* d_ws, size_t ws_size,
                              hipStream_t stream)
{
  const float* x      = (const float*)d_in[0];
  const float* wq     = (const float*)d_in[2];
  const float* bn_q   = (const float*)d_in[3];
  const float* wk     = (const float*)d_in[4];
  const float* bn_k   = (const float*)d_in[5];
  const float* wv     = (const float*)d_in[6];
  const float* bn_v   = (const float*)d_in[7];
  const float* wproj  = (const float*)d_in[8];
  const float* bproj  = (const float*)d_in[9];
  const float* bnproj = (const float*)d_in[10];
  const float* wfc1   = (const float*)d_in[11];
  const float* bfc1   = (const float*)d_in[12];
  const float* bnfc1  = (const float*)d_in[13];
  const float* wfc2   = (const float*)d_in[14];
  const float* bfc2   = (const float*)d_in[15];
  const float* bnfc2  = (const float*)d_in[16];

  char* ws = (char*)d_ws;
  const size_t TB = (size_t)T_*B_;
  uint8_t* qkv = (uint8_t*)ws;                       // TB*768*N
  uint8_t* as_ = (uint8_t*)ws + TB*768*N_;           // TB*256*N
  uint8_t* h1s = (uint8_t*)ws;                       // TB*1024*N (overlay)
  size_t off = TB*768*N_ + TB*(size_t)C_*N_;
  float* xnew = (float*)(ws + off); off += TB*(size_t)C_*N_*4;
  float* WtQ  = (float*)(ws + off); off += (size_t)C_*768*4;
  float* WtP  = (float*)(ws + off); off += (size_t)C_*C_*4;
  float* WtF1 = (float*)(ws + off); off += (size_t)C_*HD_*4;
  float* WtF2 = (float*)(ws + off); off += (size_t)HD_*C_*4;
  float* bnQ  = (float*)(ws + off); off += 4*768*4;
  float* kvb  = (float*)(ws + off); off += TB*HEADS_*DH_*DH_*4;

  dim3 blk(256);
  transW<<<dim3(8,8),blk,0,stream>>>(wq, WtQ, 256, 256, 768, 0);
  transW<<<dim3(8,8),blk,0,stream>>>(wk, WtQ, 256, 256, 768, 256);
  transW<<<dim3(8,8),blk,0,stream>>>(wv, WtQ, 256, 256, 768, 512);
  transW<<<dim3(8,8),blk,0,stream>>>(wproj, WtP, 256, 256, 256, 0);
  transW<<<dim3(8,32),blk,0,stream>>>(wfc1, WtF1, 1024, 256, 1024, 0);
  transW<<<dim3(32,8),blk,0,stream>>>(wfc2, WtF2, 256, 1024, 256, 0);
  packBn3<<<dim3(4),blk,0,stream>>>(bn_q, bn_k, bn_v, bnQ);

  // fused QKV GEMM -> spikes
  vec_gemm<C_,768,false,0,float><<<dim3(8,6,16),blk,0,stream>>>(
      x, WtQ, nullptr, bnQ, nullptr, qkv, 1.0f);
  kv_kernel<<<dim3(T_*B_*HEADS_),blk,0,stream>>>(qkv, kvb);
  attn_lif_kernel<<<dim3(4,HEADS_,B_),blk,0,stream>>>(qkv, kvb, as_);
  // proj -> xnew = x + attn spike
  vec_gemm<C_,C_,true,1,uint8_t><<<dim3(8,2,16),blk,0,stream>>>(
      as_, WtP, bproj, bnproj, x, xnew, 1.0f);
  // fc1 -> h1 spikes (overlays dead qkv/as_)
  vec_gemm<C_,HD_,true,0,float><<<dim3(8,8,16),blk,0,stream>>>(
      xnew, WtF1, bfc1, bnfc1, nullptr, h1s, 1.0f);
  // fc2 -> out = xnew + mlp spike
  vec_gemm<HD_,C_,true,1,uint8_t><<<dim3(8,2,16),blk,0,stream>>>(
      h1s, WtF2, bfc2, bnfc2, xnew, d_out, 1.0f);
}